// Round 16
// baseline (5495.950 us; speedup 1.0000x reference)
//
#include <hip/hip_runtime.h>
#include <hip/hip_cooperative_groups.h>
#include <math.h>

#define RI __restrict__

namespace {

constexpr int Hn=512, En=512, Vn=10000, Fn=1280, Pn=196, Bn=32, Tn=80;
constexpr int G4 = 2048, KX = 1792;
constexpr int NCAT = 13888;
constexpr int NVT = 157;
constexpr int J_GATE = 512, J_XP = 1792, J_LOG = 3840;
constexpr int NBLK = 256;
constexpr int WROW = 516;            // wlds row stride ([j][WROW])
constexpr int XSR  = 68;             // P1 x-stage row stride ([b][XSR])

// ---- workspace layout (float indices) ----
constexpr long O_ENC  = 0;                           // [B*P][H]
constexpr long O_W2T  = O_ENC  + (long)Bn*Pn*Hn;     // [F][H]
constexpr long O_WCAT = O_W2T  + (long)Fn*Hn;        // [512][NCAT]
constexpr long O_WIHT = O_WCAT + (long)Hn*NCAT;      // [256 grp][KX][8]
constexpr long O_C    = O_WIHT + (long)KX*G4;        // [B][H] block-private
constexpr long O_HT   = O_C    + (long)Bn*Hn;        // [H][B] coherent
constexpr long O_HID  = O_HT   + (long)Hn*Bn;        // [B][H] coherent
constexpr long O_GT   = O_HID  + (long)Bn*Hn;        // [B][F] coherent
constexpr long O_XPT  = O_GT   + (long)Bn*Fn;        // [2048 pc][B] coherent
constexpr long O_XT   = O_XPT  + (long)G4*Bn;        // [B][KX] coherent
constexpr long O_PMV  = O_XT   + (long)Bn*KX;        // [B][157] coherent
constexpr long O_PMI  = O_PMV  + (long)Bn*NVT;       // [B][157] int coherent
constexpr long O_SVAL = O_PMI  + (long)Bn*NVT;       // [B][196] coherent
constexpr long O_SEL  = O_SVAL + (long)Bn*Pn;        // [B] int coherent
constexpr long O_CNT  = O_SEL  + 64;                 // counters
// setup-only aliases inside O_ENC
constexpr long O_IHCT  = O_ENC;                      // [1280][1024]
constexpr long O_MEANT = O_ENC + (long)Fn*1024;      // [F][B]

__device__ __forceinline__ float sigm(float x){ return 1.0f/(1.0f+expf(-x)); }
__device__ __forceinline__ void fma4(float4& a, const float4 x, const float w){
  a.x += w*x.x; a.y += w*x.y; a.z += w*x.z; a.w += w*x.w;
}
__device__ __forceinline__ float dot4(const float4 a, const float4 b){
  return a.x*b.x + a.y*b.y + a.z*b.z + a.w*b.w;
}
__device__ __forceinline__ float ldc(const float* p){
  return __hip_atomic_load(p, __ATOMIC_RELAXED, __HIP_MEMORY_SCOPE_AGENT);
}
__device__ __forceinline__ void stc(float* p, float v){
  __hip_atomic_store(p, v, __ATOMIC_RELAXED, __HIP_MEMORY_SCOPE_AGENT);
}
__device__ __forceinline__ int ldci(const int* p){
  return __hip_atomic_load(p, __ATOMIC_RELAXED, __HIP_MEMORY_SCOPE_AGENT);
}
__device__ __forceinline__ void stci(int* p, int v){
  __hip_atomic_store(p, v, __ATOMIC_RELAXED, __HIP_MEMORY_SCOPE_AGENT);
}
__device__ __forceinline__ float2 ldc2(const float* p){
  union { unsigned long long u; float2 f; } c;
  c.u = __hip_atomic_load((const unsigned long long*)p,
                          __ATOMIC_RELAXED, __HIP_MEMORY_SCOPE_AGENT);
  return c.f;
}
__device__ __forceinline__ unsigned ldcu(const unsigned* p){
  return __hip_atomic_load(p, __ATOMIC_RELAXED, __HIP_MEMORY_SCOPE_AGENT);
}
__device__ __forceinline__ void incc(unsigned* p){
  __hip_atomic_fetch_add(p, 1u, __ATOMIC_RELAXED, __HIP_MEMORY_SCOPE_AGENT);
}

__device__ __forceinline__ void w1(const unsigned* a, unsigned ta){
  if (threadIdx.x == 0){
    while (ldcu(a) < ta) __builtin_amdgcn_s_sleep(2);
  }
  __syncthreads();
}
__device__ __forceinline__ void w3(const unsigned* a, unsigned ta,
                                   const unsigned* b, unsigned tb,
                                   const unsigned* c, unsigned tc){
  if (threadIdx.x == 0){
    while (ldcu(a) < ta || ldcu(b) < tb || ldcu(c) < tc) __builtin_amdgcn_s_sleep(2);
  }
  __syncthreads();
}

// ---------- transpose with dst stride ----------
__global__ __launch_bounds__(256) void k_tr_s(const float* RI src, float* RI dst,
                                              int R, int C, int S){
  __shared__ float t[32][33];
  int tc0 = blockIdx.x*32, tr0 = blockIdx.y*32;
  int lx = threadIdx.x & 31, ly = threadIdx.x >> 5;
  for (int i = ly; i < 32; i += 8){
    int r = tr0 + i, c = tc0 + lx;
    t[i][lx] = (r < R && c < C) ? src[(long)r*C + c] : 0.f;
  }
  __syncthreads();
  for (int i = ly; i < 32; i += 8){
    int c = tc0 + i, r = tr0 + lx;
    if (c < C && r < R) dst[(long)c*S + r] = t[lx][i];
  }
}

// ---------- wih transpose: WIHT[pc>>3][k][pc&7], pc=(j&511)*4+(j>>9) ----------
__global__ __launch_bounds__(256) void k_tr_wih(const float* RI src, float* RI ws){
  __shared__ float t[32][33];
  int tk0 = blockIdx.x*32, tj0 = blockIdx.y*32;
  int lx = threadIdx.x & 31, ly = threadIdx.x >> 5;
  for (int i = ly; i < 32; i += 8){
    int j = tj0 + i, k = tk0 + lx;
    t[i][lx] = src[(long)j*KX + k];
  }
  __syncthreads();
  for (int i = ly; i < 32; i += 8){
    int k = tk0 + i, j = tj0 + lx;
    int pc = ((j & 511) << 2) | (j >> 9);
    ws[O_WIHT + ((long)(pc >> 3)*KX + k)*8 + (pc & 7)] = t[lx][i];
  }
}

// ---------- meanT[f][b] ----------
__global__ __launch_bounds__(256) void k_mean(const float* RI feat, float* RI ws){
  int blk = blockIdx.x;
  int b = blk / 5, ft = blk % 5;
  int f = ft*256 + threadIdx.x;
  float s = 0.f;
  const float* fp = feat + (long)b*Pn*Fn + f;
  for (int p = 0; p < Pn; ++p) s += fp[(long)p*Fn];
  ws[O_MEANT + (long)f*Bn + b] = s * (1.0f/Pn);
}

// ---------- h0,c0 ----------
__global__ __launch_bounds__(512) void k_h0c0(const float* RI ihb, const float* RI icb,
                                              float* RI ws){
  int tid = threadIdx.x;
  int jl = tid & 63, bq = tid >> 6;
  int j = blockIdx.x*64 + jl;
  const float* wp = ws + O_IHCT + j;
  const float* xp = ws + O_MEANT + bq*4;
  float4 acc = make_float4(0,0,0,0);
  for (int k = 0; k < Fn; ++k){
    float w = wp[(long)k*1024];
    float4 x = *(const float4*)(xp + (long)k*Bn);
    fma4(acc, x, w);
  }
  float va[4] = {acc.x, acc.y, acc.z, acc.w};
  if (j < Hn){
    float bias = ihb[j];
    #pragma unroll
    for (int m = 0; m < 4; ++m)
      ws[O_HT + (long)j*Bn + (bq*4+m)] = va[m] + bias;
  } else {
    int j2 = j - Hn;
    float bias = icb[j2];
    #pragma unroll
    for (int m = 0; m < 4; ++m)
      ws[O_C + (long)(bq*4+m)*Hn + j2] = va[m] + bias;
  }
}

// ---------- enc_proj ----------
__global__ __launch_bounds__(512) void k_encproj(const float* RI feat, const float* RI w2b,
                                                 float* RI ws){
  __shared__ __align__(16) float xs[64*65];
  const int blk = blockIdx.x;
  const int rt = blk >> 2, ct = blk & 3;
  const int r0 = rt*64, j0 = ct*128;
  const int tid = threadIdx.x;
  const int jq = tid & 31, rg = tid >> 5;
  const int rw = tid >> 3, kc = (tid & 7)*8;
  const float* w2t = ws + O_W2T + j0 + jq*4;
  float4 a0 = make_float4(0,0,0,0), a1 = a0, a2 = a0, a3 = a0;
  for (int k0 = 0; k0 < Fn; k0 += 64){
    __syncthreads();
    {
      const float* fp = feat + (long)(r0+rw)*Fn + k0 + kc;
      float4 v0 = *(const float4*)(fp);
      float4 v1 = *(const float4*)(fp + 4);
      float* xr = xs + rw*65 + kc;
      xr[0]=v0.x; xr[1]=v0.y; xr[2]=v0.z; xr[3]=v0.w;
      xr[4]=v1.x; xr[5]=v1.y; xr[6]=v1.z; xr[7]=v1.w;
    }
    __syncthreads();
    #pragma unroll 4
    for (int kk = 0; kk < 64; ++kk){
      float4 w = *(const float4*)(w2t + (long)(k0+kk)*Hn);
      const float* xp = xs + (rg*4)*65 + kk;
      fma4(a0, w, xp[0]);
      fma4(a1, w, xp[65]);
      fma4(a2, w, xp[130]);
      fma4(a3, w, xp[195]);
    }
  }
  float4 b4 = *(const float4*)(w2b + j0 + jq*4);
  float4 out[4] = {a0,a1,a2,a3};
  #pragma unroll
  for (int m = 0; m < 4; ++m){
    long r = r0 + rg*4 + m;
    float4 o = out[m];
    o.x += b4.x; o.y += b4.y; o.z += b4.z; o.w += b4.w;
    *(float4*)(ws + O_ENC + r*Hn + j0 + jq*4) = o;
  }
}

// ---------- the whole 80-step decode: dataflow-counter sync ----------
__global__ __launch_bounds__(512) void k_decode(
    const float* RI feat, const float* RI emb, const float* RI vaw, const float* RI vab,
    const float* RI w1b, const float* RI gb, const float* RI bih, const float* RI bhh,
    const float* RI outb, float* RI ws, float* RI dout)
{
  __shared__ __align__(16) float wlds[64*WROW];  // 129 KB pinned WCAT slice [j][k]
  __shared__ __align__(16) float sbuf[4608];     // 18 KB phase scratch
  const int blk = blockIdx.x, tid = threadIdx.x;
  const int jl = tid & 63, bq = tid >> 6;
  unsigned* cnt = (unsigned*)(ws + O_CNT);
  unsigned* C_H   = cnt + 0;
  unsigned* C_P1  = cnt + 32;
  unsigned* C_HID = cnt + 64;
  unsigned* C_GT  = cnt + 96;
  unsigned* C_XP  = cnt + 128;
  unsigned* C_LOG = cnt + 160;
  unsigned* C_XT  = cnt + 192;
  #define C_SC(b)  (cnt + 256 + (b)*8)
  #define C_SEL(b) (cnt + 512 + (b)*8)

  if (blk < 217){
    const float* wg = ws + O_WCAT + blk*64;
    for (int idx = tid; idx < 512*64; idx += 512){
      int k = idx >> 6, j = idx & 63;
      wlds[j*WROW + k] = wg[(long)k*NCAT + j];
    }
  }
  __syncthreads();

  for (int t = 0; t <= Tn; ++t){
    // ====== P1: h-GEMM — w as lane-b128 [j][4k], x as broadcast-b128 [b][4k] ======
    if (blk < 217){
      if (t > 0) w1(C_H, 256u*t);
      bool p1act = (t == Tn) ? (blk >= 60) : !(t == 0 && blk >= 60);
      if (p1act){
        float4 acc = make_float4(0,0,0,0);
        float2 pre0 = ldc2(ws + O_HT + tid*2);
        float2 pre1 = ldc2(ws + O_HT + 1024 + tid*2);
        const int k0a = (tid*2) >> 5, b0a = (tid*2) & 31;        // chunk-local k, b
        const int k1a = k0a + 32;
        for (int c8 = 0; c8 < 8; ++c8){
          __syncthreads();
          sbuf[b0a*XSR + k0a]     = pre0.x;
          sbuf[(b0a+1)*XSR + k0a] = pre0.y;
          sbuf[b0a*XSR + k1a]     = pre1.x;
          sbuf[(b0a+1)*XSR + k1a] = pre1.y;
          __syncthreads();
          if (c8 < 7){
            pre0 = ldc2(ws + O_HT + (long)(c8+1)*2048 + tid*2);
            pre1 = ldc2(ws + O_HT + (long)(c8+1)*2048 + 1024 + tid*2);
          }
          const float* wr = wlds + jl*WROW + c8*64;
          const float* x0 = sbuf + (bq*4+0)*XSR;
          const float* x1 = sbuf + (bq*4+1)*XSR;
          const float* x2 = sbuf + (bq*4+2)*XSR;
          const float* x3 = sbuf + (bq*4+3)*XSR;
          #pragma unroll
          for (int g = 0; g < 16; ++g){
            float4 w4 = *(const float4*)(wr + g*4);
            acc.x += dot4(w4, *(const float4*)(x0 + g*4));
            acc.y += dot4(w4, *(const float4*)(x1 + g*4));
            acc.z += dot4(w4, *(const float4*)(x2 + g*4));
            acc.w += dot4(w4, *(const float4*)(x3 + g*4));
          }
        }
        __syncthreads();                  // sbuf free for epilogue staging
        const int j = blk*64 + jl;
        if (blk < 8){                      // hid -> HID[b][H]
          float bias = w1b[j];
          stc(ws + O_HID + (long)(bq*4+0)*Hn + j, acc.x + bias);
          stc(ws + O_HID + (long)(bq*4+1)*Hn + j, acc.y + bias);
          stc(ws + O_HID + (long)(bq*4+2)*Hn + j, acc.z + bias);
          stc(ws + O_HID + (long)(bq*4+3)*Hn + j, acc.w + bias);
        } else if (blk < 28){              // gate -> GT[b][f]
          int f = j - J_GATE;
          float bias = gb[f];
          stc(ws + O_GT + (long)(bq*4+0)*Fn + f, sigm(acc.x + bias));
          stc(ws + O_GT + (long)(bq*4+1)*Fn + f, sigm(acc.y + bias));
          stc(ws + O_GT + (long)(bq*4+2)*Fn + f, sigm(acc.z + bias));
          stc(ws + O_GT + (long)(bq*4+3)*Fn + f, sigm(acc.w + bias));
        } else if (blk < 60){              // xpart -> XPT[pc][B] via LDS stage
          int j2 = j - J_XP;
          float bias = bih[j2] + bhh[j2];
          sbuf[jl*33 + bq*4+0] = acc.x + bias;
          sbuf[jl*33 + bq*4+1] = acc.y + bias;
          sbuf[jl*33 + bq*4+2] = acc.z + bias;
          sbuf[jl*33 + bq*4+3] = acc.w + bias;
          __syncthreads();
          #pragma unroll
          for (int r = 0; r < 4; ++r){
            int idx = r*512 + tid;
            int row = idx >> 5, b = idx & 31;
            int j2r = (blk-28)*64 + row;
            int pc = ((j2r & 511) << 2) | (j2r >> 9);
            stc(ws + O_XPT + (long)pc*Bn + b, sbuf[row*33 + b]);
          }
        } else {                           // logits_{t-1} + argmax partials
          int v = j - J_LOG;
          float lv[4];
          if (v < Vn){
            float bias = outb[v];
            lv[0]=acc.x+bias; lv[1]=acc.y+bias; lv[2]=acc.z+bias; lv[3]=acc.w+bias;
            #pragma unroll
            for (int m = 0; m < 4; ++m)
              dout[((long)(bq*4+m)*Tn + (t-1))*Vn + v] = lv[m];
          } else {
            lv[0]=lv[1]=lv[2]=lv[3]=-1e30f;
          }
          int tile = blk - 60;
          #pragma unroll
          for (int m = 0; m < 4; ++m){
            float bv = lv[m]; int bi = v;
            #pragma unroll
            for (int off = 32; off; off >>= 1){
              float ov = __shfl_down(bv, off, 64);
              int   oi = __shfl_down(bi, off, 64);
              if (ov > bv || (ov == bv && oi < bi)){ bv = ov; bi = oi; }
            }
            if (jl == 0){
              int b = bq*4 + m;
              stc (ws + O_PMV + (long)b*NVT + tile, bv);
              stci((int*)(ws + O_PMI) + (long)b*NVT + tile, bi);
            }
          }
        }
      }
      __syncthreads();
      if (tid == 0){
        unsigned* role = (blk < 8) ? C_HID : (blk < 28) ? C_GT
                       : (blk < 60) ? C_XP : C_LOG;
        incc(role); incc(C_P1);
      }
    }
    if (t == Tn) break;

    // ============== P2a: scores (224 blocks) + argmax finalize (32) ==============
    if (blk < 224){
      const int b = blk & 31, part = blk >> 5;
      w1(C_HID, 8u*(t+1));
      float* hid_s = sbuf;
      float* va_s  = sbuf + 512;
      float* sv    = sbuf + 1024;
      hid_s[tid] = ldc(ws + O_HID + (long)b*Hn + tid);
      va_s[tid]  = vaw[tid];
      __syncthreads();
      const int w = tid >> 6, l = tid & 63;
      const int p0 = part*28;
      const float* eb = ws + O_ENC + (long)b*Pn*Hn;
      #pragma unroll 2
      for (int p = p0 + w; p < p0 + 28; p += 8){
        const float* er = eb + (long)p*Hn;
        float4 e0 = *(const float4*)(er + l*4);
        float4 e1 = *(const float4*)(er + 256 + l*4);
        float4 h0 = *(const float4*)(hid_s + l*4);
        float4 h1 = *(const float4*)(hid_s + 256 + l*4);
        float4 v0 = *(const float4*)(va_s + l*4);
        float4 v1 = *(const float4*)(va_s + 256 + l*4);
        float s = fmaxf(h0.x+e0.x,0.f)*v0.x + fmaxf(h0.y+e0.y,0.f)*v0.y
                + fmaxf(h0.z+e0.z,0.f)*v0.z + fmaxf(h0.w+e0.w,0.f)*v0.w
                + fmaxf(h1.x+e1.x,0.f)*v1.x + fmaxf(h1.y+e1.y,0.f)*v1.y
                + fmaxf(h1.z+e1.z,0.f)*v1.z + fmaxf(h1.w+e1.w,0.f)*v1.w;
        #pragma unroll
        for (int off = 32; off; off >>= 1) s += __shfl_down(s, off, 64);
        if (l == 0) sv[p - p0] = s + vab[0];
      }
      __syncthreads();
      if (tid < 28) stc(ws + O_SVAL + (long)b*Pn + p0 + tid, sv[tid]);
      __syncthreads();
      if (tid == 0) incc(C_SC(b));
    } else {
      const int b = blk - 224;
      w1(C_LOG, 157u*(t+1));
      if (t == 0){
        if (tid == 0) stci((int*)(ws + O_SEL) + b, 1);
      } else if (tid < 64){
        float bv = -1e30f; int bi = 0x7fffffff;
        for (int q = tid; q < NVT; q += 64){
          float cv = ldc(ws + O_PMV + (long)b*NVT + q);
          if (cv > bv){ bv = cv; bi = ldci((const int*)(ws + O_PMI) + (long)b*NVT + q); }
        }
        #pragma unroll
        for (int off = 32; off; off >>= 1){
          float ov = __shfl_down(bv, off, 64);
          int   oi = __shfl_down(bi, off, 64);
          if (ov > bv || (ov == bv && oi < bi)){ bv = ov; bi = oi; }
        }
        if (tid == 0) stci((int*)(ws + O_SEL) + b, bi);
      }
      __syncthreads();
      if (tid == 0) incc(C_SEL(b));
    }

    // ============== P2b: softmax + ctx + emb -> XT[b][k] (all 256) ==============
    {
      const int b = blk & 31, fr = blk >> 5;
      const int f0 = fr*160;
      w3(C_SC(b), 7u*(t+1), C_SEL(b), (unsigned)(t+1), C_GT, 20u*(t+1));
      float* svl = sbuf;
      float* wts = sbuf + 208;
      if (tid < Pn) svl[tid] = ldc(ws + O_SVAL + (long)b*Pn + tid);
      if (tid == 0) ((int*)sbuf)[450] = ldci((const int*)(ws + O_SEL) + b);
      __syncthreads();
      if (tid < 64){
        float m = -1e30f;
        for (int p = tid; p < Pn; p += 64) m = fmaxf(m, svl[p]);
        #pragma unroll
        for (int off = 32; off; off >>= 1) m = fmaxf(m, __shfl_xor(m, off, 64));
        float sm = 0.f;
        for (int p = tid; p < Pn; p += 64) sm += expf(svl[p] - m);
        #pragma unroll
        for (int off = 32; off; off >>= 1) sm += __shfl_xor(sm, off, 64);
        if (tid == 0){ sbuf[448] = m; sbuf[449] = 1.0f/sm; }
      }
      __syncthreads();
      if (tid < Pn){
        float wv = expf(svl[tid] - sbuf[448]) * sbuf[449];
        wts[tid] = wv;
        if (fr == 0)
          dout[(long)Bn*Tn*Vn + 2L*Bn*Hn + ((long)b*Tn + t)*Pn + tid] = wv;
      }
      __syncthreads();
      const int pp = tid / 160, fl = tid - pp*160;
      float a = 0.f;
      if (tid < 480){
        const int p0 = pp*66, pn = (pp == 2) ? 64 : 66;
        const float* fp = feat + ((long)b*Pn + p0)*Fn + f0 + fl;
        const float* wl = wts + p0;
        float s0=0,s1=0,s2=0,s3=0,s4=0,s5=0,s6=0,s7=0;
        int p = 0;
        for (; p + 8 <= pn; p += 8){
          s0 += wl[p+0]*fp[(long)(p+0)*Fn];
          s1 += wl[p+1]*fp[(long)(p+1)*Fn];
          s2 += wl[p+2]*fp[(long)(p+2)*Fn];
          s3 += wl[p+3]*fp[(long)(p+3)*Fn];
          s4 += wl[p+4]*fp[(long)(p+4)*Fn];
          s5 += wl[p+5]*fp[(long)(p+5)*Fn];
          s6 += wl[p+6]*fp[(long)(p+6)*Fn];
          s7 += wl[p+7]*fp[(long)(p+7)*Fn];
        }
        for (; p < pn; ++p) s0 += wl[p]*fp[(long)p*Fn];
        a = ((s0+s1)+(s2+s3)) + ((s4+s5)+(s6+s7));
        if (pp > 0) sbuf[512 + (pp-1)*160 + fl] = a;
      }
      __syncthreads();
      if (tid < 160){
        float tot = a + sbuf[512 + tid] + sbuf[672 + tid];
        int f = f0 + tid;
        tot *= ldc(ws + O_GT + (long)b*Fn + f);
        stc(ws + O_XT + (long)b*KX + En + f, tot);
      }
      if (fr == 0){
        int row = ((int*)sbuf)[450];
        stc(ws + O_XT + (long)b*KX + tid, emb[(long)row*En + tid]);
      }
      __syncthreads();
      if (tid == 0) incc(C_XT);
    }

    // ============== P3: Wih GEMM ([kl][36] swizzled staging, b128 reads) + LSTM ======
    {
      w3(C_XT, 256u*(t+1), C_XP, 32u*(t+1), C_P1, 217u*(t+1));
      const int c = tid & 7, ks = tid >> 3;      // ks 0..63
      const int pc0 = blk*8;
      const float* wg = ws + O_WIHT + (long)blk*KX*8;
      float4 acc4[8];
      #pragma unroll
      for (int q = 0; q < 8; ++q) acc4[q] = make_float4(0,0,0,0);
      float2 pre[4];
      #pragma unroll
      for (int r = 0; r < 4; ++r){
        int flat = r*1024 + tid*2;
        pre[r] = ldc2(ws + O_XT + (long)(flat >> 7)*KX + (flat & 127));
      }
      for (int ch = 0; ch < 14; ++ch){
        __syncthreads();
        #pragma unroll
        for (int r = 0; r < 4; ++r){
          int flat = r*1024 + tid*2;
          int kl = flat & 127, b = flat >> 7;
          int sw = ((kl >> 2) & 7) << 2;
          float* xd = sbuf + kl*36;
          xd[b ^ sw]        = pre[r].x;
          xd[36 + (b ^ sw)] = pre[r].y;
        }
        __syncthreads();
        if (ch < 13){
          long k0n = (long)(ch+1)*128;
          #pragma unroll
          for (int r = 0; r < 4; ++r){
            int flat = r*1024 + tid*2;
            pre[r] = ldc2(ws + O_XT + (long)(flat >> 7)*KX + k0n + (flat & 127));
          }
        }
        const long kg0 = (long)ch*128;
        #pragma unroll
        for (int kk = 0; kk < 2; ++kk){
          int kl = ks*2 + kk;
          float w = wg[(kg0 + kl)*8 + c];
          int sw = ((kl >> 2) & 7) << 2;
          const float* xq = sbuf + kl*36;
          #pragma unroll
          for (int q = 0; q < 8; ++q){
            float4 x = *(const float4*)(xq + ((q*4) ^ sw));
            fma4(acc4[q], x, w);
          }
        }
      }
      #pragma unroll
      for (int off = 8; off <= 32; off <<= 1){
        #pragma unroll
        for (int q = 0; q < 8; ++q){
          acc4[q].x += __shfl_xor(acc4[q].x, off, 64);
          acc4[q].y += __shfl_xor(acc4[q].y, off, 64);
          acc4[q].z += __shfl_xor(acc4[q].z, off, 64);
          acc4[q].w += __shfl_xor(acc4[q].w, off, 64);
        }
      }
      __syncthreads();                   // staging dead; reuse sbuf
      const int wv = tid >> 6, lane = tid & 63;
      if (lane < 8){
        float* rb = sbuf + (wv*8 + lane)*32;
        #pragma unroll
        for (int q = 0; q < 8; ++q) *(float4*)(rb + q*4) = acc4[q];
      }
      __syncthreads();
      if (tid < 256){
        int cc = tid >> 5, b = tid & 31;
        float s = 0.f;
        #pragma unroll
        for (int w2 = 0; w2 < 8; ++w2) s += sbuf[(w2*8 + cc)*32 + b];
        s += ldc(ws + O_XPT + (long)(pc0 + cc)*Bn + b);
        sbuf[2048 + cc*32 + b] = s;
      }
      __syncthreads();
      if (tid < 64){
        int il = tid >> 5, b = tid & 31;
        int i = blk*2 + il;
        float gi  = sbuf[2048 + (il*4+0)*32 + b];
        float gf  = sbuf[2048 + (il*4+1)*32 + b];
        float gg2 = sbuf[2048 + (il*4+2)*32 + b];
        float go  = sbuf[2048 + (il*4+3)*32 + b];
        float c_ = ws[O_C + (long)b*Hn + i];
        float cn = sigm(gf)*c_ + sigm(gi)*tanhf(gg2);
        float hn = sigm(go)*tanhf(cn);
        ws[O_C + (long)b*Hn + i] = cn;
        stc(ws + O_HT + (long)i*Bn + b, hn);
        if (t == Tn-1){
          dout[(long)Bn*Tn*Vn + (long)b*Hn + i] = hn;
          dout[(long)Bn*Tn*Vn + (long)Bn*Hn + (long)b*Hn + i] = cn;
        }
      }
      __syncthreads();
      if (tid == 0) incc(C_H);
    }
  }
  #undef C_SC
  #undef C_SEL
}

} // anonymous namespace

extern "C" void kernel_launch(void* const* d_in, const int* in_sizes, int n_in,
                              void* d_out, int out_size, void* d_ws, size_t ws_size,
                              hipStream_t stream)
{
  (void)in_sizes; (void)n_in; (void)out_size; (void)ws_size;
  const float* feat = (const float*)d_in[0];
  const float* emb  = (const float*)d_in[3];
  const float* w1w  = (const float*)d_in[4];
  const float* w1b  = (const float*)d_in[5];
  const float* w2w  = (const float*)d_in[6];
  const float* w2b  = (const float*)d_in[7];
  const float* vaw  = (const float*)d_in[8];
  const float* vab  = (const float*)d_in[9];
  const float* wih  = (const float*)d_in[10];
  const float* whh  = (const float*)d_in[11];
  const float* bih  = (const float*)d_in[12];
  const float* bhh  = (const float*)d_in[13];
  const float* outw = (const float*)d_in[14];
  const float* outb = (const float*)d_in[15];
  const float* ihw  = (const float*)d_in[16];
  const float* ihb  = (const float*)d_in[17];
  const float* icw  = (const float*)d_in[18];
  const float* icb  = (const float*)d_in[19];
  const float* gw   = (const float*)d_in[20];
  const float* gb   = (const float*)d_in[21];
  float* ws  = (float*)d_ws;
  float* out = (float*)d_out;

  hipMemsetAsync((char*)d_ws + O_CNT*sizeof(float), 0, 4096, stream);

  k_tr_s<<<dim3(40,16),  256, 0, stream>>>(ihw,  ws + O_IHCT,       Hn, Fn, 1024);
  k_tr_s<<<dim3(40,16),  256, 0, stream>>>(icw,  ws + O_IHCT + 512, Hn, Fn, 1024);
  k_mean<<<160, 256, 0, stream>>>(feat, ws);
  k_h0c0<<<16, 512, 0, stream>>>(ihb, icb, ws);
  k_tr_s<<<dim3(16,16),  256, 0, stream>>>(w1w,  ws + O_WCAT,          Hn, Hn, NCAT);
  k_tr_s<<<dim3(16,40),  256, 0, stream>>>(gw,   ws + O_WCAT + J_GATE, Fn, Hn, NCAT);
  k_tr_s<<<dim3(16,64),  256, 0, stream>>>(whh,  ws + O_WCAT + J_XP,   G4, Hn, NCAT);
  k_tr_s<<<dim3(16,313), 256, 0, stream>>>(outw, ws + O_WCAT + J_LOG,  Vn, Hn, NCAT);
  k_tr_wih<<<dim3(56,64), 256, 0, stream>>>(wih, ws);
  k_tr_s<<<dim3(40,16),  256, 0, stream>>>(w2w,  ws + O_W2T,           Hn, Fn, Hn);
  k_encproj<<<392, 512, 0, stream>>>(feat, w2b, ws);

  void* kargs[] = { (void*)&feat, (void*)&emb, (void*)&vaw, (void*)&vab,
                    (void*)&w1b, (void*)&gb, (void*)&bih, (void*)&bhh,
                    (void*)&outb, (void*)&ws, (void*)&out };
  hipLaunchCooperativeKernel((const void*)k_decode, dim3(NBLK), dim3(512),
                             kargs, 0, stream);
}

// Round 17
// 5358.390 us; speedup vs baseline: 1.0257x; 1.0257x over previous
//
#include <hip/hip_runtime.h>
#include <hip/hip_cooperative_groups.h>
#include <math.h>

#define RI __restrict__

namespace {

constexpr int Hn=512, En=512, Vn=10000, Fn=1280, Pn=196, Bn=32, Tn=80;
constexpr int G4 = 2048, KX = 1792;
constexpr int NCAT = 13888;
constexpr int NVT = 157;
constexpr int J_GATE = 512, J_XP = 1792, J_LOG = 3840;
constexpr int NBLK = 256;

// ---- workspace layout (float indices) ----
constexpr long O_ENC  = 0;                           // [B*P][H]
constexpr long O_W2T  = O_ENC  + (long)Bn*Pn*Hn;     // [F][H]
constexpr long O_WCAT = O_W2T  + (long)Fn*Hn;        // [512][NCAT]
constexpr long O_WIHT = O_WCAT + (long)Hn*NCAT;      // [256 grp][KX][8]
constexpr long O_C    = O_WIHT + (long)KX*G4;        // [B][H] block-private
constexpr long O_HT   = O_C    + (long)Bn*Hn;        // [H][B] coherent
constexpr long O_HID  = O_HT   + (long)Hn*Bn;        // [B][H] coherent
constexpr long O_GT   = O_HID  + (long)Bn*Hn;        // [B][F] coherent
constexpr long O_XPT  = O_GT   + (long)Bn*Fn;        // [2048 pc][B] coherent
constexpr long O_XT   = O_XPT  + (long)G4*Bn;        // [B][KX] coherent
constexpr long O_PMV  = O_XT   + (long)Bn*KX;        // [B][157] coherent
constexpr long O_PMI  = O_PMV  + (long)Bn*NVT;       // [B][157] int coherent
constexpr long O_SVAL = O_PMI  + (long)Bn*NVT;       // [B][196] coherent
constexpr long O_SEL  = O_SVAL + (long)Bn*Pn;        // [B] int coherent
constexpr long O_CNT  = O_SEL  + 64;                 // counters
// setup-only aliases inside O_ENC
constexpr long O_IHCT  = O_ENC;                      // [1280][1024]
constexpr long O_MEANT = O_ENC + (long)Fn*1024;      // [F][B]

__device__ __forceinline__ float sigm(float x){ return 1.0f/(1.0f+expf(-x)); }
__device__ __forceinline__ void fma4(float4& a, const float4 x, const float w){
  a.x += w*x.x; a.y += w*x.y; a.z += w*x.z; a.w += w*x.w;
}
__device__ __forceinline__ float ldc(const float* p){
  return __hip_atomic_load(p, __ATOMIC_RELAXED, __HIP_MEMORY_SCOPE_AGENT);
}
__device__ __forceinline__ void stc(float* p, float v){
  __hip_atomic_store(p, v, __ATOMIC_RELAXED, __HIP_MEMORY_SCOPE_AGENT);
}
__device__ __forceinline__ int ldci(const int* p){
  return __hip_atomic_load(p, __ATOMIC_RELAXED, __HIP_MEMORY_SCOPE_AGENT);
}
__device__ __forceinline__ void stci(int* p, int v){
  __hip_atomic_store(p, v, __ATOMIC_RELAXED, __HIP_MEMORY_SCOPE_AGENT);
}
__device__ __forceinline__ float2 ldc2(const float* p){
  union { unsigned long long u; float2 f; } c;
  c.u = __hip_atomic_load((const unsigned long long*)p,
                          __ATOMIC_RELAXED, __HIP_MEMORY_SCOPE_AGENT);
  return c.f;
}
__device__ __forceinline__ unsigned ldcu(const unsigned* p){
  return __hip_atomic_load(p, __ATOMIC_RELAXED, __HIP_MEMORY_SCOPE_AGENT);
}
__device__ __forceinline__ void incc(unsigned* p){
  __hip_atomic_fetch_add(p, 1u, __ATOMIC_RELAXED, __HIP_MEMORY_SCOPE_AGENT);
}

__device__ __forceinline__ void w1(const unsigned* a, unsigned ta){
  if (threadIdx.x == 0){
    while (ldcu(a) < ta) __builtin_amdgcn_s_sleep(2);
  }
  __syncthreads();
}
__device__ __forceinline__ void w3(const unsigned* a, unsigned ta,
                                   const unsigned* b, unsigned tb,
                                   const unsigned* c, unsigned tc){
  if (threadIdx.x == 0){
    while (ldcu(a) < ta || ldcu(b) < tb || ldcu(c) < tc) __builtin_amdgcn_s_sleep(2);
  }
  __syncthreads();
}

// ---------- transpose with dst stride ----------
__global__ __launch_bounds__(256) void k_tr_s(const float* RI src, float* RI dst,
                                              int R, int C, int S){
  __shared__ float t[32][33];
  int tc0 = blockIdx.x*32, tr0 = blockIdx.y*32;
  int lx = threadIdx.x & 31, ly = threadIdx.x >> 5;
  for (int i = ly; i < 32; i += 8){
    int r = tr0 + i, c = tc0 + lx;
    t[i][lx] = (r < R && c < C) ? src[(long)r*C + c] : 0.f;
  }
  __syncthreads();
  for (int i = ly; i < 32; i += 8){
    int c = tc0 + i, r = tr0 + lx;
    if (c < C && r < R) dst[(long)c*S + r] = t[lx][i];
  }
}

// ---------- wih transpose: WIHT[pc>>3][k][pc&7], pc=(j&511)*4+(j>>9) ----------
__global__ __launch_bounds__(256) void k_tr_wih(const float* RI src, float* RI ws){
  __shared__ float t[32][33];
  int tk0 = blockIdx.x*32, tj0 = blockIdx.y*32;
  int lx = threadIdx.x & 31, ly = threadIdx.x >> 5;
  for (int i = ly; i < 32; i += 8){
    int j = tj0 + i, k = tk0 + lx;
    t[i][lx] = src[(long)j*KX + k];
  }
  __syncthreads();
  for (int i = ly; i < 32; i += 8){
    int k = tk0 + i, j = tj0 + lx;
    int pc = ((j & 511) << 2) | (j >> 9);
    ws[O_WIHT + ((long)(pc >> 3)*KX + k)*8 + (pc & 7)] = t[lx][i];
  }
}

// ---------- meanT[f][b] ----------
__global__ __launch_bounds__(256) void k_mean(const float* RI feat, float* RI ws){
  int blk = blockIdx.x;
  int b = blk / 5, ft = blk % 5;
  int f = ft*256 + threadIdx.x;
  float s = 0.f;
  const float* fp = feat + (long)b*Pn*Fn + f;
  for (int p = 0; p < Pn; ++p) s += fp[(long)p*Fn];
  ws[O_MEANT + (long)f*Bn + b] = s * (1.0f/Pn);
}

// ---------- h0,c0 ----------
__global__ __launch_bounds__(512) void k_h0c0(const float* RI ihb, const float* RI icb,
                                              float* RI ws){
  int tid = threadIdx.x;
  int jl = tid & 63, bq = tid >> 6;
  int j = blockIdx.x*64 + jl;
  const float* wp = ws + O_IHCT + j;
  const float* xp = ws + O_MEANT + bq*4;
  float4 acc = make_float4(0,0,0,0);
  for (int k = 0; k < Fn; ++k){
    float w = wp[(long)k*1024];
    float4 x = *(const float4*)(xp + (long)k*Bn);
    fma4(acc, x, w);
  }
  float va[4] = {acc.x, acc.y, acc.z, acc.w};
  if (j < Hn){
    float bias = ihb[j];
    #pragma unroll
    for (int m = 0; m < 4; ++m)
      ws[O_HT + (long)j*Bn + (bq*4+m)] = va[m] + bias;
  } else {
    int j2 = j - Hn;
    float bias = icb[j2];
    #pragma unroll
    for (int m = 0; m < 4; ++m)
      ws[O_C + (long)(bq*4+m)*Hn + j2] = va[m] + bias;
  }
}

// ---------- enc_proj ----------
__global__ __launch_bounds__(512) void k_encproj(const float* RI feat, const float* RI w2b,
                                                 float* RI ws){
  __shared__ __align__(16) float xs[64*65];
  const int blk = blockIdx.x;
  const int rt = blk >> 2, ct = blk & 3;
  const int r0 = rt*64, j0 = ct*128;
  const int tid = threadIdx.x;
  const int jq = tid & 31, rg = tid >> 5;
  const int rw = tid >> 3, kc = (tid & 7)*8;
  const float* w2t = ws + O_W2T + j0 + jq*4;
  float4 a0 = make_float4(0,0,0,0), a1 = a0, a2 = a0, a3 = a0;
  for (int k0 = 0; k0 < Fn; k0 += 64){
    __syncthreads();
    {
      const float* fp = feat + (long)(r0+rw)*Fn + k0 + kc;
      float4 v0 = *(const float4*)(fp);
      float4 v1 = *(const float4*)(fp + 4);
      float* xr = xs + rw*65 + kc;
      xr[0]=v0.x; xr[1]=v0.y; xr[2]=v0.z; xr[3]=v0.w;
      xr[4]=v1.x; xr[5]=v1.y; xr[6]=v1.z; xr[7]=v1.w;
    }
    __syncthreads();
    #pragma unroll 4
    for (int kk = 0; kk < 64; ++kk){
      float4 w = *(const float4*)(w2t + (long)(k0+kk)*Hn);
      const float* xp = xs + (rg*4)*65 + kk;
      fma4(a0, w, xp[0]);
      fma4(a1, w, xp[65]);
      fma4(a2, w, xp[130]);
      fma4(a3, w, xp[195]);
    }
  }
  float4 b4 = *(const float4*)(w2b + j0 + jq*4);
  float4 out[4] = {a0,a1,a2,a3};
  #pragma unroll
  for (int m = 0; m < 4; ++m){
    long r = r0 + rg*4 + m;
    float4 o = out[m];
    o.x += b4.x; o.y += b4.y; o.z += b4.z; o.w += b4.w;
    *(float4*)(ws + O_ENC + r*Hn + j0 + jq*4) = o;
  }
}

// ---------- the whole 80-step decode: dataflow-counter sync ----------
__global__ __launch_bounds__(512) void k_decode(
    const float* RI feat, const float* RI emb, const float* RI vaw, const float* RI vab,
    const float* RI w1b, const float* RI gb, const float* RI bih, const float* RI bhh,
    const float* RI outb, float* RI ws, float* RI dout)
{
  __shared__ __align__(16) float wlds[32768];    // 128 KB pinned WCAT slice [k][64 j]
  __shared__ __align__(16) float sbuf[4608];     // 18 KB phase scratch
  const int blk = blockIdx.x, tid = threadIdx.x;
  const int jl = tid & 63, bq = tid >> 6;
  unsigned* cnt = (unsigned*)(ws + O_CNT);
  unsigned* C_H   = cnt + 0;
  unsigned* C_P1  = cnt + 32;
  unsigned* C_HID = cnt + 64;
  unsigned* C_GT  = cnt + 96;
  unsigned* C_XP  = cnt + 128;
  unsigned* C_LOG = cnt + 160;
  unsigned* C_XT  = cnt + 192;
  #define C_SC(b)  (cnt + 256 + (b)*8)
  #define C_SEL(b) (cnt + 512 + (b)*8)

  if (blk < 217){
    const float* wg = ws + O_WCAT + blk*64;
    for (int idx = tid; idx < 512*64; idx += 512){
      int k = idx >> 6, j = idx & 63;
      wlds[idx] = wg[(long)k*NCAT + j];
    }
  }
  __syncthreads();

  for (int t = 0; t <= Tn; ++t){
    // ============== P1: unified h-GEMM (LDS weights, LDS-chunked HT) ==============
    if (blk < 217){
      if (t > 0) w1(C_H, 256u*t);
      bool p1act = (t == Tn) ? (blk >= 60) : !(t == 0 && blk >= 60);
      if (p1act){
        float4 acc = make_float4(0,0,0,0);
        float2 pre0 = ldc2(ws + O_HT + tid*2);
        float2 pre1 = ldc2(ws + O_HT + 1024 + tid*2);
        for (int c8 = 0; c8 < 8; ++c8){
          __syncthreads();
          *(float2*)(sbuf + tid*2) = pre0;
          *(float2*)(sbuf + 1024 + tid*2) = pre1;
          __syncthreads();
          if (c8 < 7){
            pre0 = ldc2(ws + O_HT + (long)(c8+1)*2048 + tid*2);
            pre1 = ldc2(ws + O_HT + (long)(c8+1)*2048 + 1024 + tid*2);
          }
          #pragma unroll 8
          for (int kk = 0; kk < 64; ++kk){
            float w = wlds[(long)(c8*64 + kk)*64 + jl];
            float4 x = *(const float4*)(sbuf + kk*32 + bq*4);
            fma4(acc, x, w);
          }
        }
        __syncthreads();                  // sbuf free for epilogue staging
        const int j = blk*64 + jl;
        if (blk < 8){                      // hid -> HID[b][H]
          float bias = w1b[j];
          stc(ws + O_HID + (long)(bq*4+0)*Hn + j, acc.x + bias);
          stc(ws + O_HID + (long)(bq*4+1)*Hn + j, acc.y + bias);
          stc(ws + O_HID + (long)(bq*4+2)*Hn + j, acc.z + bias);
          stc(ws + O_HID + (long)(bq*4+3)*Hn + j, acc.w + bias);
        } else if (blk < 28){              // gate -> GT[b][f]
          int f = j - J_GATE;
          float bias = gb[f];
          stc(ws + O_GT + (long)(bq*4+0)*Fn + f, sigm(acc.x + bias));
          stc(ws + O_GT + (long)(bq*4+1)*Fn + f, sigm(acc.y + bias));
          stc(ws + O_GT + (long)(bq*4+2)*Fn + f, sigm(acc.z + bias));
          stc(ws + O_GT + (long)(bq*4+3)*Fn + f, sigm(acc.w + bias));
        } else if (blk < 60){              // xpart -> XPT[pc][B] via LDS stage
          int j2 = j - J_XP;
          float bias = bih[j2] + bhh[j2];
          sbuf[jl*33 + bq*4+0] = acc.x + bias;
          sbuf[jl*33 + bq*4+1] = acc.y + bias;
          sbuf[jl*33 + bq*4+2] = acc.z + bias;
          sbuf[jl*33 + bq*4+3] = acc.w + bias;
          __syncthreads();
          #pragma unroll
          for (int r = 0; r < 4; ++r){
            int idx = r*512 + tid;
            int row = idx >> 5, b = idx & 31;
            int j2r = (blk-28)*64 + row;
            int pc = ((j2r & 511) << 2) | (j2r >> 9);
            stc(ws + O_XPT + (long)pc*Bn + b, sbuf[row*33 + b]);
          }
        } else {                           // logits_{t-1} + argmax partials
          int v = j - J_LOG;
          float lv[4];
          if (v < Vn){
            float bias = outb[v];
            lv[0]=acc.x+bias; lv[1]=acc.y+bias; lv[2]=acc.z+bias; lv[3]=acc.w+bias;
            #pragma unroll
            for (int m = 0; m < 4; ++m)
              dout[((long)(bq*4+m)*Tn + (t-1))*Vn + v] = lv[m];
          } else {
            lv[0]=lv[1]=lv[2]=lv[3]=-1e30f;
          }
          int tile = blk - 60;
          #pragma unroll
          for (int m = 0; m < 4; ++m){
            float bv = lv[m]; int bi = v;
            #pragma unroll
            for (int off = 32; off; off >>= 1){
              float ov = __shfl_down(bv, off, 64);
              int   oi = __shfl_down(bi, off, 64);
              if (ov > bv || (ov == bv && oi < bi)){ bv = ov; bi = oi; }
            }
            if (jl == 0){
              int b = bq*4 + m;
              stc (ws + O_PMV + (long)b*NVT + tile, bv);
              stci((int*)(ws + O_PMI) + (long)b*NVT + tile, bi);
            }
          }
        }
      }
      __syncthreads();
      if (tid == 0){
        unsigned* role = (blk < 8) ? C_HID : (blk < 28) ? C_GT
                       : (blk < 60) ? C_XP : C_LOG;
        incc(role); incc(C_P1);
      }
    }
    if (t == Tn) break;

    // ============== P2a: scores (224 blocks) + argmax finalize (32) ==============
    if (blk < 224){
      const int b = blk & 31, part = blk >> 5;
      w1(C_HID, 8u*(t+1));
      float* hid_s = sbuf;
      float* va_s  = sbuf + 512;
      float* sv    = sbuf + 1024;
      hid_s[tid] = ldc(ws + O_HID + (long)b*Hn + tid);
      va_s[tid]  = vaw[tid];
      __syncthreads();
      const int w = tid >> 6, l = tid & 63;
      const int p0 = part*28;
      const float* eb = ws + O_ENC + (long)b*Pn*Hn;
      #pragma unroll 2
      for (int p = p0 + w; p < p0 + 28; p += 8){
        const float* er = eb + (long)p*Hn;
        float4 e0 = *(const float4*)(er + l*4);
        float4 e1 = *(const float4*)(er + 256 + l*4);
        float4 h0 = *(const float4*)(hid_s + l*4);
        float4 h1 = *(const float4*)(hid_s + 256 + l*4);
        float4 v0 = *(const float4*)(va_s + l*4);
        float4 v1 = *(const float4*)(va_s + 256 + l*4);
        float s = fmaxf(h0.x+e0.x,0.f)*v0.x + fmaxf(h0.y+e0.y,0.f)*v0.y
                + fmaxf(h0.z+e0.z,0.f)*v0.z + fmaxf(h0.w+e0.w,0.f)*v0.w
                + fmaxf(h1.x+e1.x,0.f)*v1.x + fmaxf(h1.y+e1.y,0.f)*v1.y
                + fmaxf(h1.z+e1.z,0.f)*v1.z + fmaxf(h1.w+e1.w,0.f)*v1.w;
        #pragma unroll
        for (int off = 32; off; off >>= 1) s += __shfl_down(s, off, 64);
        if (l == 0) sv[p - p0] = s + vab[0];
      }
      __syncthreads();
      if (tid < 28) stc(ws + O_SVAL + (long)b*Pn + p0 + tid, sv[tid]);
      __syncthreads();
      if (tid == 0) incc(C_SC(b));
    } else {
      const int b = blk - 224;
      w1(C_LOG, 157u*(t+1));
      if (t == 0){
        if (tid == 0) stci((int*)(ws + O_SEL) + b, 1);
      } else if (tid < 64){
        float bv = -1e30f; int bi = 0x7fffffff;
        for (int q = tid; q < NVT; q += 64){
          float cv = ldc(ws + O_PMV + (long)b*NVT + q);
          if (cv > bv){ bv = cv; bi = ldci((const int*)(ws + O_PMI) + (long)b*NVT + q); }
        }
        #pragma unroll
        for (int off = 32; off; off >>= 1){
          float ov = __shfl_down(bv, off, 64);
          int   oi = __shfl_down(bi, off, 64);
          if (ov > bv || (ov == bv && oi < bi)){ bv = ov; bi = oi; }
        }
        if (tid == 0) stci((int*)(ws + O_SEL) + b, bi);
      }
      __syncthreads();
      if (tid == 0) incc(C_SEL(b));
    }

    // ============== P2b: softmax + ctx + emb -> XT[b][k] (all 256) ==============
    {
      const int b = blk & 31, fr = blk >> 5;
      const int f0 = fr*160;
      w3(C_SC(b), 7u*(t+1), C_SEL(b), (unsigned)(t+1), C_GT, 20u*(t+1));
      float* svl = sbuf;
      float* wts = sbuf + 208;
      if (tid < Pn) svl[tid] = ldc(ws + O_SVAL + (long)b*Pn + tid);
      if (tid == 0) ((int*)sbuf)[450] = ldci((const int*)(ws + O_SEL) + b);
      __syncthreads();
      if (tid < 64){
        float m = -1e30f;
        for (int p = tid; p < Pn; p += 64) m = fmaxf(m, svl[p]);
        #pragma unroll
        for (int off = 32; off; off >>= 1) m = fmaxf(m, __shfl_xor(m, off, 64));
        float sm = 0.f;
        for (int p = tid; p < Pn; p += 64) sm += expf(svl[p] - m);
        #pragma unroll
        for (int off = 32; off; off >>= 1) sm += __shfl_xor(sm, off, 64);
        if (tid == 0){ sbuf[448] = m; sbuf[449] = 1.0f/sm; }
      }
      __syncthreads();
      if (tid < Pn){
        float wv = expf(svl[tid] - sbuf[448]) * sbuf[449];
        wts[tid] = wv;
        if (fr == 0)
          dout[(long)Bn*Tn*Vn + 2L*Bn*Hn + ((long)b*Tn + t)*Pn + tid] = wv;
      }
      __syncthreads();
      const int pp = tid / 160, fl = tid - pp*160;
      float a = 0.f;
      if (tid < 480){
        const int p0 = pp*66, pn = (pp == 2) ? 64 : 66;
        const float* fp = feat + ((long)b*Pn + p0)*Fn + f0 + fl;
        const float* wl = wts + p0;
        float s0=0,s1=0,s2=0,s3=0,s4=0,s5=0,s6=0,s7=0;
        int p = 0;
        for (; p + 8 <= pn; p += 8){
          s0 += wl[p+0]*fp[(long)(p+0)*Fn];
          s1 += wl[p+1]*fp[(long)(p+1)*Fn];
          s2 += wl[p+2]*fp[(long)(p+2)*Fn];
          s3 += wl[p+3]*fp[(long)(p+3)*Fn];
          s4 += wl[p+4]*fp[(long)(p+4)*Fn];
          s5 += wl[p+5]*fp[(long)(p+5)*Fn];
          s6 += wl[p+6]*fp[(long)(p+6)*Fn];
          s7 += wl[p+7]*fp[(long)(p+7)*Fn];
        }
        for (; p < pn; ++p) s0 += wl[p]*fp[(long)p*Fn];
        a = ((s0+s1)+(s2+s3)) + ((s4+s5)+(s6+s7));
        if (pp > 0) sbuf[512 + (pp-1)*160 + fl] = a;
      }
      __syncthreads();
      if (tid < 160){
        float tot = a + sbuf[512 + tid] + sbuf[672 + tid];
        int f = f0 + tid;
        tot *= ldc(ws + O_GT + (long)b*Fn + f);
        stc(ws + O_XT + (long)b*KX + En + f, tot);
      }
      if (fr == 0){
        int row = ((int*)sbuf)[450];
        stc(ws + O_XT + (long)b*KX + tid, emb[(long)row*En + tid]);
      }
      __syncthreads();
      if (tid == 0) incc(C_XT);
    }

    // ============== P3: Wih GEMM ([kl][36] swizzled staging, b128 reads) + LSTM ======
    {
      w3(C_XT, 256u*(t+1), C_XP, 32u*(t+1), C_P1, 217u*(t+1));
      const int c = tid & 7, ks = tid >> 3;      // ks 0..63
      const int pc0 = blk*8;
      const float* wg = ws + O_WIHT + (long)blk*KX*8;
      float4 acc4[8];
      #pragma unroll
      for (int q = 0; q < 8; ++q) acc4[q] = make_float4(0,0,0,0);
      float2 pre[4];
      #pragma unroll
      for (int r = 0; r < 4; ++r){
        int flat = r*1024 + tid*2;
        pre[r] = ldc2(ws + O_XT + (long)(flat >> 7)*KX + (flat & 127));
      }
      for (int ch = 0; ch < 14; ++ch){
        __syncthreads();
        #pragma unroll
        for (int r = 0; r < 4; ++r){
          int flat = r*1024 + tid*2;
          int kl = flat & 127, b = flat >> 7;
          int sw = ((kl >> 2) & 7) << 2;
          float* xd = sbuf + kl*36;
          xd[b ^ sw]        = pre[r].x;
          xd[36 + (b ^ sw)] = pre[r].y;
        }
        __syncthreads();
        if (ch < 13){
          long k0n = (long)(ch+1)*128;
          #pragma unroll
          for (int r = 0; r < 4; ++r){
            int flat = r*1024 + tid*2;
            pre[r] = ldc2(ws + O_XT + (long)(flat >> 7)*KX + k0n + (flat & 127));
          }
        }
        const long kg0 = (long)ch*128;
        #pragma unroll
        for (int kk = 0; kk < 2; ++kk){
          int kl = ks*2 + kk;
          float w = wg[(kg0 + kl)*8 + c];
          int sw = ((kl >> 2) & 7) << 2;
          const float* xq = sbuf + kl*36;
          #pragma unroll
          for (int q = 0; q < 8; ++q){
            float4 x = *(const float4*)(xq + ((q*4) ^ sw));
            fma4(acc4[q], x, w);
          }
        }
      }
      #pragma unroll
      for (int off = 8; off <= 32; off <<= 1){
        #pragma unroll
        for (int q = 0; q < 8; ++q){
          acc4[q].x += __shfl_xor(acc4[q].x, off, 64);
          acc4[q].y += __shfl_xor(acc4[q].y, off, 64);
          acc4[q].z += __shfl_xor(acc4[q].z, off, 64);
          acc4[q].w += __shfl_xor(acc4[q].w, off, 64);
        }
      }
      __syncthreads();                   // staging dead; reuse sbuf
      const int wv = tid >> 6, lane = tid & 63;
      if (lane < 8){
        float* rb = sbuf + (wv*8 + lane)*32;
        #pragma unroll
        for (int q = 0; q < 8; ++q) *(float4*)(rb + q*4) = acc4[q];
      }
      __syncthreads();
      if (tid < 256){
        int cc = tid >> 5, b = tid & 31;
        float s = 0.f;
        #pragma unroll
        for (int w2 = 0; w2 < 8; ++w2) s += sbuf[(w2*8 + cc)*32 + b];
        s += ldc(ws + O_XPT + (long)(pc0 + cc)*Bn + b);
        sbuf[2048 + cc*32 + b] = s;
      }
      __syncthreads();
      if (tid < 64){
        int il = tid >> 5, b = tid & 31;
        int i = blk*2 + il;
        float gi  = sbuf[2048 + (il*4+0)*32 + b];
        float gf  = sbuf[2048 + (il*4+1)*32 + b];
        float gg2 = sbuf[2048 + (il*4+2)*32 + b];
        float go  = sbuf[2048 + (il*4+3)*32 + b];
        float c_ = ws[O_C + (long)b*Hn + i];
        float cn = sigm(gf)*c_ + sigm(gi)*tanhf(gg2);
        float hn = sigm(go)*tanhf(cn);
        ws[O_C + (long)b*Hn + i] = cn;
        stc(ws + O_HT + (long)i*Bn + b, hn);
        if (t == Tn-1){
          dout[(long)Bn*Tn*Vn + (long)b*Hn + i] = hn;
          dout[(long)Bn*Tn*Vn + (long)Bn*Hn + (long)b*Hn + i] = cn;
        }
      }
      __syncthreads();
      if (tid == 0) incc(C_H);
    }
  }
  #undef C_SC
  #undef C_SEL
}

} // anonymous namespace

extern "C" void kernel_launch(void* const* d_in, const int* in_sizes, int n_in,
                              void* d_out, int out_size, void* d_ws, size_t ws_size,
                              hipStream_t stream)
{
  (void)in_sizes; (void)n_in; (void)out_size; (void)ws_size;
  const float* feat = (const float*)d_in[0];
  const float* emb  = (const float*)d_in[3];
  const float* w1w  = (const float*)d_in[4];
  const float* w1b  = (const float*)d_in[5];
  const float* w2w  = (const float*)d_in[6];
  const float* w2b  = (const float*)d_in[7];
  const float* vaw  = (const float*)d_in[8];
  const float* vab  = (const float*)d_in[9];
  const float* wih  = (const float*)d_in[10];
  const float* whh  = (const float*)d_in[11];
  const float* bih  = (const float*)d_in[12];
  const float* bhh  = (const float*)d_in[13];
  const float* outw = (const float*)d_in[14];
  const float* outb = (const float*)d_in[15];
  const float* ihw  = (const float*)d_in[16];
  const float* ihb  = (const float*)d_in[17];
  const float* icw  = (const float*)d_in[18];
  const float* icb  = (const float*)d_in[19];
  const float* gw   = (const float*)d_in[20];
  const float* gb   = (const float*)d_in[21];
  float* ws  = (float*)d_ws;
  float* out = (float*)d_out;

  hipMemsetAsync((char*)d_ws + O_CNT*sizeof(float), 0, 4096, stream);

  k_tr_s<<<dim3(40,16),  256, 0, stream>>>(ihw,  ws + O_IHCT,       Hn, Fn, 1024);
  k_tr_s<<<dim3(40,16),  256, 0, stream>>>(icw,  ws + O_IHCT + 512, Hn, Fn, 1024);
  k_mean<<<160, 256, 0, stream>>>(feat, ws);
  k_h0c0<<<16, 512, 0, stream>>>(ihb, icb, ws);
  k_tr_s<<<dim3(16,16),  256, 0, stream>>>(w1w,  ws + O_WCAT,          Hn, Hn, NCAT);
  k_tr_s<<<dim3(16,40),  256, 0, stream>>>(gw,   ws + O_WCAT + J_GATE, Fn, Hn, NCAT);
  k_tr_s<<<dim3(16,64),  256, 0, stream>>>(whh,  ws + O_WCAT + J_XP,   G4, Hn, NCAT);
  k_tr_s<<<dim3(16,313), 256, 0, stream>>>(outw, ws + O_WCAT + J_LOG,  Vn, Hn, NCAT);
  k_tr_wih<<<dim3(56,64), 256, 0, stream>>>(wih, ws);
  k_tr_s<<<dim3(40,16),  256, 0, stream>>>(w2w,  ws + O_W2T,           Hn, Fn, Hn);
  k_encproj<<<392, 512, 0, stream>>>(feat, w2b, ws);

  void* kargs[] = { (void*)&feat, (void*)&emb, (void*)&vaw, (void*)&vab,
                    (void*)&w1b, (void*)&gb, (void*)&bih, (void*)&bhh,
                    (void*)&outb, (void*)&ws, (void*)&out };
  hipLaunchCooperativeKernel((const void*)k_decode, dim3(NBLK), dim3(512),
                             kargs, 0, stream);
}